// Round 2
// baseline (155.497 us; speedup 1.0000x reference)
//
#include <hip/hip_runtime.h>
#include <math.h>

#define TEMP_F 0.07f
#define NCON 20
#define LDIM 512
#define NROWS 32768
#define NSEL 16384

// ws layout:
// float [0..511]      ebar_sz
// float [512..1023]   ebar_nsz
// u32   [1024]        keep-mask sz  (bit j set => concept j kept)
// u32   [1025]        keep-mask nsz
// u32   [1026]        ticket (last-block election)
// float [1088..1215]  128 partial-sum slots
// u32   [2048 .. 2048+NROWS)  packed counts: low16 = #sz hits, high16 = #nsz hits

// ---------------------------------------------------------------------------
// Kernel 1: prep + scan-histogram, 129 blocks x 256 threads.
// Blocks 0..127: block b owns rows [b*256, b*256+256); scans ALL indices
//   (32768 ints x2 branches, L2/L3-resident) counting hits into LDS, then
//   writes the 256 packed counts. No global atomics, no zeroing dependency.
// Block 128: concept-mean embeddings, keep masks, zero slots/ticket/out.
// ---------------------------------------------------------------------------
__global__ __launch_bounds__(256) void prep_hist_kernel(const float* __restrict__ all_emb,
                                                        const int* __restrict__ Psz,
                                                        const int* __restrict__ Pnsz,
                                                        const int* __restrict__ sz_idx,
                                                        const int* __restrict__ nsz_idx,
                                                        float* __restrict__ ws,
                                                        float* __restrict__ out) {
    const int tid = threadIdx.x;
    if (blockIdx.x < 128) {
        __shared__ unsigned lc[256];
        lc[tid] = 0u;
        __syncthreads();
        const unsigned base = blockIdx.x * 256u;
        const int4* s4 = (const int4*)sz_idx;
        const int4* n4 = (const int4*)nsz_idx;
#pragma unroll 4
        for (int k = tid; k < NSEL / 4; k += 256) {
            const int4 a = s4[k];
            unsigned d;
            d = (unsigned)a.x - base; if (d < 256u) atomicAdd(&lc[d], 1u);
            d = (unsigned)a.y - base; if (d < 256u) atomicAdd(&lc[d], 1u);
            d = (unsigned)a.z - base; if (d < 256u) atomicAdd(&lc[d], 1u);
            d = (unsigned)a.w - base; if (d < 256u) atomicAdd(&lc[d], 1u);
            const int4 b = n4[k];
            d = (unsigned)b.x - base; if (d < 256u) atomicAdd(&lc[d], 65536u);
            d = (unsigned)b.y - base; if (d < 256u) atomicAdd(&lc[d], 65536u);
            d = (unsigned)b.z - base; if (d < 256u) atomicAdd(&lc[d], 65536u);
            d = (unsigned)b.w - base; if (d < 256u) atomicAdd(&lc[d], 65536u);
        }
        __syncthreads();
        ((unsigned*)ws)[2048 + base + tid] = lc[tid];
        return;
    }

    // block 128: prep
    float s1 = 0.f, s2 = 0.f, n1 = 0.f, n2 = 0.f;
#pragma unroll
    for (int k = 0; k < 5; ++k) {
        s1 += all_emb[Psz[k]  * LDIM + tid];
        s2 += all_emb[Psz[k]  * LDIM + tid + 256];
        n1 += all_emb[Pnsz[k] * LDIM + tid];
        n2 += all_emb[Pnsz[k] * LDIM + tid + 256];
    }
    ws[tid]             = s1 * 0.2f;  // mean over 5 (duplicates counted, matches ref)
    ws[tid + 256]       = s2 * 0.2f;
    ws[512 + tid]       = n1 * 0.2f;
    ws[512 + tid + 256] = n2 * 0.2f;
    if (tid < 128) ws[1088 + tid] = 0.f;            // slots
    if (tid == 0) {
        unsigned m = (1u << NCON) - 1u, m2 = (1u << NCON) - 1u;
#pragma unroll
        for (int k = 0; k < 5; ++k) { m &= ~(1u << Psz[k]); m2 &= ~(1u << Pnsz[k]); }
        ((unsigned*)ws)[1024] = m;
        ((unsigned*)ws)[1025] = m2;
        ((unsigned*)ws)[1026] = 0u;                 // ticket
        out[0] = 0.f;                               // d_out poisoned every launch
    }
}

__device__ inline float dot4(float4 a, float4 b) {
    return a.x * b.x + a.y * b.y + a.z * b.z + a.w * b.w;
}

// ---------------------------------------------------------------------------
// Kernel 2: one streaming pass. 2048 blocks x 256 threads = 8192 waves,
// 4 consecutive rows per wave. All selected rows' loads are issued BEFORE any
// compute (deep in-wave MLP), count==0 rows skipped (saves ~37% of hg traffic).
// Block sums -> 128 spread slots -> ticket-elected last block reduces slots.
// ---------------------------------------------------------------------------
__global__ __launch_bounds__(256) void fused_kernel(const float* __restrict__ hg,
                                                    const float* __restrict__ sim,
                                                    float* __restrict__ ws,
                                                    float* __restrict__ out) {
    const float4* hg4   = (const float4*)hg;
    const unsigned* cnt = (const unsigned*)ws + 2048;
    const unsigned msz  = ((const unsigned*)ws)[1024];
    const unsigned mnsz = ((const unsigned*)ws)[1025];
    float* slot         = ws + 1088;
    unsigned* ticket    = (unsigned*)ws + 1026;

    const int wave = threadIdx.x >> 6;
    const int lane = threadIdx.x & 63;
    const int r0   = (blockIdx.x * 4 + wave) * 4;   // rows r0..r0+3

    const float4* eb4 = (const float4*)ws;          // 128 f4 ebar_sz + 128 f4 ebar_nsz
    const float4 es0 = eb4[lane * 2],       es1 = eb4[lane * 2 + 1];
    const float4 en0 = eb4[128 + lane * 2], en1 = eb4[128 + lane * 2 + 1];

    const uint4 c4 = *(const uint4*)(cnt + r0);
    const unsigned cc[4] = {c4.x, c4.y, c4.z, c4.w};

    // prefetch phase: issue every selected row's loads, no compute between
    float4 a0[4], a1[4];
    float sv[4];
    const float4* rp = hg4 + (size_t)r0 * (LDIM / 4) + lane * 2;
    const bool c20 = lane < NCON;
#pragma unroll
    for (int i = 0; i < 4; ++i) {
        if (cc[i]) {
            a0[i] = rp[i * (LDIM / 4)];
            a1[i] = rp[i * (LDIM / 4) + 1];
            sv[i] = c20 ? sim[(size_t)(r0 + i) * NCON + lane] : 0.f;
        }
    }

    const float invT = 1.0f / TEMP_F;
    float acc = 0.f;
#pragma unroll
    for (int i = 0; i < 4; ++i) {
        if (!cc[i]) continue;
        float ss = dot4(a0[i], a0[i]) + dot4(a1[i], a1[i]);
        float ds = dot4(a0[i], es0) + dot4(a1[i], es1);
        float dn = dot4(a0[i], en0) + dot4(a1[i], en1);
        const float ex = expf(sv[i] * invT);
        float e_s = (c20 && (msz  & (1u << lane))) ? ex : 0.f;
        float e_n = (c20 && (mnsz & (1u << lane))) ? ex : 0.f;
#pragma unroll
        for (int off = 32; off; off >>= 1) {
            ss  += __shfl_xor(ss, off);
            ds  += __shfl_xor(ds, off);
            dn  += __shfl_xor(dn, off);
            e_s += __shfl_xor(e_s, off);
            e_n += __shfl_xor(e_n, off);
        }
        const float rn = invT / fmaxf(sqrtf(ss), 1e-12f);
        acc += (float)(cc[i] & 0xffffu) * (logf(e_s) - ds * rn)
             + (float)(cc[i] >> 16)     * (logf(e_n) - dn * rn);
    }

    // block reduce (full butterfly => every lane holds the wave sum)
    __shared__ float red[4];
    __shared__ unsigned lastflag;
    if (lane == 0) red[wave] = acc;
    __syncthreads();
    if (threadIdx.x == 0) {
        const float bsum = red[0] + red[1] + red[2] + red[3];
        atomicAdd(&slot[blockIdx.x & 127], bsum);   // spread over 128 addresses
        __threadfence();
        const unsigned t = atomicAdd(ticket, 1u);
        lastflag = (t == gridDim.x - 1) ? 1u : 0u;
    }
    __syncthreads();
    if (lastflag && threadIdx.x < 64) {
        // atomic reads: device-coherent across XCD L2s
        float v = atomicAdd(&slot[threadIdx.x], 0.f)
                + atomicAdd(&slot[threadIdx.x + 64], 0.f);
#pragma unroll
        for (int off = 32; off; off >>= 1) v += __shfl_xor(v, off);
        if (threadIdx.x == 0) out[0] = v * (1.0f / NSEL);
    }
}

extern "C" void kernel_launch(void* const* d_in, const int* in_sizes, int n_in,
                              void* d_out, int out_size, void* d_ws, size_t ws_size,
                              hipStream_t stream) {
    const float* hg      = (const float*)d_in[0];
    const float* hg_corr = (const float*)d_in[1];
    const float* all_emb = (const float*)d_in[2];
    const int*   sz_idx  = (const int*)d_in[3];
    const int*   nsz_idx = (const int*)d_in[4];
    const int*   Psz     = (const int*)d_in[5];
    const int*   Pnsz    = (const int*)d_in[6];
    float* out = (float*)d_out;
    float* ws  = (float*)d_ws;

    prep_hist_kernel<<<129, 256, 0, stream>>>(all_emb, Psz, Pnsz,
                                              sz_idx, nsz_idx, ws, out);
    fused_kernel<<<2048, 256, 0, stream>>>(hg, hg_corr, ws, out);
}

// Round 3
// 118.246 us; speedup vs baseline: 1.3150x; 1.3150x over previous
//
#include <hip/hip_runtime.h>
#include <math.h>

#define TEMP_F 0.07f
#define NCON 20
#define LDIM 512
#define NROWS 32768
#define NSEL 16384
#define BSUM 34816  // float offset of 8192 per-block partial sums (= 2048 + NROWS)

// ws layout (floats unless noted):
// [0..511]      ebar_sz
// [512..1023]   ebar_nsz
// u32 [1024]    keep-mask sz  (bit j set => concept j kept)
// u32 [1025]    keep-mask nsz
// u32 [2048 .. 2048+NROWS)   packed counts: low16 = #sz hits, high16 = #nsz hits
// [BSUM .. BSUM+8192)        per-block partial sums (plain stores, no atomics)

// ---------------------------------------------------------------------------
// Kernel 1: prep + scan-histogram, 129 blocks x 256 threads (proven in r2).
// Blocks 0..127: block b owns rows [b*256, b*256+256); scans all indices
//   (L2/L3-resident) counting hits into LDS, writes 256 packed counts.
// Block 128: concept-mean embeddings + keep masks.
// ---------------------------------------------------------------------------
__global__ __launch_bounds__(256) void prep_hist_kernel(const float* __restrict__ all_emb,
                                                        const int* __restrict__ Psz,
                                                        const int* __restrict__ Pnsz,
                                                        const int* __restrict__ sz_idx,
                                                        const int* __restrict__ nsz_idx,
                                                        float* __restrict__ ws) {
    const int tid = threadIdx.x;
    if (blockIdx.x < 128) {
        __shared__ unsigned lc[256];
        lc[tid] = 0u;
        __syncthreads();
        const unsigned base = blockIdx.x * 256u;
        const int4* s4 = (const int4*)sz_idx;
        const int4* n4 = (const int4*)nsz_idx;
#pragma unroll 4
        for (int k = tid; k < NSEL / 4; k += 256) {
            const int4 a = s4[k];
            unsigned d;
            d = (unsigned)a.x - base; if (d < 256u) atomicAdd(&lc[d], 1u);
            d = (unsigned)a.y - base; if (d < 256u) atomicAdd(&lc[d], 1u);
            d = (unsigned)a.z - base; if (d < 256u) atomicAdd(&lc[d], 1u);
            d = (unsigned)a.w - base; if (d < 256u) atomicAdd(&lc[d], 1u);
            const int4 b = n4[k];
            d = (unsigned)b.x - base; if (d < 256u) atomicAdd(&lc[d], 65536u);
            d = (unsigned)b.y - base; if (d < 256u) atomicAdd(&lc[d], 65536u);
            d = (unsigned)b.z - base; if (d < 256u) atomicAdd(&lc[d], 65536u);
            d = (unsigned)b.w - base; if (d < 256u) atomicAdd(&lc[d], 65536u);
        }
        __syncthreads();
        ((unsigned*)ws)[2048 + base + tid] = lc[tid];
        return;
    }

    // block 128: concept means + masks
    float s1 = 0.f, s2 = 0.f, n1 = 0.f, n2 = 0.f;
#pragma unroll
    for (int k = 0; k < 5; ++k) {
        s1 += all_emb[Psz[k]  * LDIM + tid];
        s2 += all_emb[Psz[k]  * LDIM + tid + 256];
        n1 += all_emb[Pnsz[k] * LDIM + tid];
        n2 += all_emb[Pnsz[k] * LDIM + tid + 256];
    }
    ws[tid]             = s1 * 0.2f;  // mean over 5 (duplicates counted, matches ref)
    ws[tid + 256]       = s2 * 0.2f;
    ws[512 + tid]       = n1 * 0.2f;
    ws[512 + tid + 256] = n2 * 0.2f;
    if (tid == 0) {
        unsigned m = (1u << NCON) - 1u, m2 = (1u << NCON) - 1u;
#pragma unroll
        for (int k = 0; k < 5; ++k) { m &= ~(1u << Psz[k]); m2 &= ~(1u << Pnsz[k]); }
        ((unsigned*)ws)[1024] = m;
        ((unsigned*)ws)[1025] = m2;
    }
}

__device__ inline float dot4(float4 a, float4 b) {
    return a.x * b.x + a.y * b.y + a.z * b.z + a.w * b.w;
}

// ---------------------------------------------------------------------------
// Kernel 2: streaming pass, ONE ROW PER WAVE (r0's proven BW-bound shape).
// 8192 blocks x 256 threads = 32768 waves. count==0 rows exit immediately
// (saves ~37% of hg traffic). Block partial sum -> plain store, NO atomics.
// ---------------------------------------------------------------------------
__global__ __launch_bounds__(256) void fused_kernel(const float* __restrict__ hg,
                                                    const float* __restrict__ sim,
                                                    float* __restrict__ ws) {
    const int wave = threadIdx.x >> 6;
    const int lane = threadIdx.x & 63;
    const int r    = blockIdx.x * 4 + wave;

    const unsigned c = ((const unsigned*)ws)[2048 + r];  // wave-uniform broadcast
    float acc = 0.f;

    if (c != 0u) {
        const float4* eb4 = (const float4*)ws;  // 128 f4 ebar_sz, 128 f4 ebar_nsz
        const float4 es0 = eb4[lane * 2],       es1 = eb4[lane * 2 + 1];
        const float4 en0 = eb4[128 + lane * 2], en1 = eb4[128 + lane * 2 + 1];
        const unsigned msz  = ((const unsigned*)ws)[1024];
        const unsigned mnsz = ((const unsigned*)ws)[1025];

        const float4* rp = (const float4*)hg + (size_t)r * (LDIM / 4) + lane * 2;
        const float4 a0 = rp[0];
        const float4 a1 = rp[1];

        const bool c20 = lane < NCON;
        const float sv = c20 ? sim[(size_t)r * NCON + lane] : 0.f;

        float ss = dot4(a0, a0) + dot4(a1, a1);
        float ds = dot4(a0, es0) + dot4(a1, es1);
        float dn = dot4(a0, en0) + dot4(a1, en1);

        const float invT = 1.0f / TEMP_F;
        const float ex = expf(sv * invT);
        float e_s = (c20 && (msz  & (1u << lane))) ? ex : 0.f;
        float e_n = (c20 && (mnsz & (1u << lane))) ? ex : 0.f;

#pragma unroll
        for (int off = 32; off; off >>= 1) {
            ss  += __shfl_xor(ss, off);
            ds  += __shfl_xor(ds, off);
            dn  += __shfl_xor(dn, off);
            e_s += __shfl_xor(e_s, off);
            e_n += __shfl_xor(e_n, off);
        }

        const float rn = invT / fmaxf(sqrtf(ss), 1e-12f);
        acc = (float)(c & 0xffffu) * (logf(e_s) - ds * rn)
            + (float)(c >> 16)     * (logf(e_n) - dn * rn);
    }

    __shared__ float red[4];
    if (lane == 0) red[wave] = acc;
    __syncthreads();
    if (threadIdx.x == 0)
        ws[BSUM + blockIdx.x] = red[0] + red[1] + red[2] + red[3];  // plain store
}

// ---------------------------------------------------------------------------
// Kernel 3: 1 block x 256 threads sums the 8192 block partials (32 KB).
// Inter-dispatch visibility of plain stores is guaranteed (HSA release at
// dispatch end / acquire at dispatch start). Writes out unconditionally
// (out is poisoned before every launch).
// ---------------------------------------------------------------------------
__global__ __launch_bounds__(256) void reduce_kernel(const float* __restrict__ ws,
                                                     float* __restrict__ out) {
    const float4* b4 = (const float4*)(ws + BSUM);  // 2048 float4
    float s = 0.f;
#pragma unroll
    for (int k = threadIdx.x; k < 2048; k += 256) {
        const float4 v = b4[k];
        s += (v.x + v.y) + (v.z + v.w);
    }
#pragma unroll
    for (int off = 32; off; off >>= 1) s += __shfl_xor(s, off);
    __shared__ float red[4];
    if ((threadIdx.x & 63) == 0) red[threadIdx.x >> 6] = s;
    __syncthreads();
    if (threadIdx.x == 0)
        out[0] = (red[0] + red[1] + red[2] + red[3]) * (1.0f / NSEL);
}

extern "C" void kernel_launch(void* const* d_in, const int* in_sizes, int n_in,
                              void* d_out, int out_size, void* d_ws, size_t ws_size,
                              hipStream_t stream) {
    const float* hg      = (const float*)d_in[0];
    const float* hg_corr = (const float*)d_in[1];
    const float* all_emb = (const float*)d_in[2];
    const int*   sz_idx  = (const int*)d_in[3];
    const int*   nsz_idx = (const int*)d_in[4];
    const int*   Psz     = (const int*)d_in[5];
    const int*   Pnsz    = (const int*)d_in[6];
    float* out = (float*)d_out;
    float* ws  = (float*)d_ws;

    prep_hist_kernel<<<129, 256, 0, stream>>>(all_emb, Psz, Pnsz,
                                              sz_idx, nsz_idx, ws);
    fused_kernel<<<8192, 256, 0, stream>>>(hg, hg_corr, ws);
    reduce_kernel<<<1, 256, 0, stream>>>(ws, out);
}

// Round 4
// 108.839 us; speedup vs baseline: 1.4287x; 1.0864x over previous
//
#include <hip/hip_runtime.h>
#include <math.h>

#define TEMP_F 0.07f
#define NCON 20
#define LDIM 512
#define NROWS 32768
#define NSEL 16384

// ws layout (floats unless noted):
// [0..511]      ebar_sz
// [512..1023]   ebar_nsz
// u32 [1024]    keep-mask sz  (bit j set => concept j kept)
// u32 [1025]    keep-mask nsz
// [2048 .. 2048+2*NROWS)  t2[r] = float2{ t_sz(r), t_nsz(r) }  (256 KB table)

// ---------------------------------------------------------------------------
// Kernel 1: prep — 1 block x 512 threads (r0's proven shape).
// Concept-mean embeddings, keep masks, zero out (out is poisoned pre-launch).
// ---------------------------------------------------------------------------
__global__ __launch_bounds__(512) void prep_kernel(const float* __restrict__ all_emb,
                                                   const int* __restrict__ Psz,
                                                   const int* __restrict__ Pnsz,
                                                   float* __restrict__ ws,
                                                   float* __restrict__ out) {
    const int l = threadIdx.x;
    float ssz = 0.f, snsz = 0.f;
#pragma unroll
    for (int k = 0; k < 5; ++k) {
        ssz  += all_emb[Psz[k]  * LDIM + l];
        snsz += all_emb[Pnsz[k] * LDIM + l];
    }
    ws[l]       = ssz  * 0.2f;   // mean over 5 (duplicates counted, matches ref)
    ws[512 + l] = snsz * 0.2f;
    if (l == 0) {
        unsigned m = (1u << NCON) - 1u, m2 = (1u << NCON) - 1u;
#pragma unroll
        for (int k = 0; k < 5; ++k) { m &= ~(1u << Psz[k]); m2 &= ~(1u << Pnsz[k]); }
        ((unsigned*)ws)[1024] = m;
        ((unsigned*)ws)[1025] = m2;
        out[0] = 0.f;
    }
}

__device__ inline float dot4(float4 a, float4 b) {
    return a.x * b.x + a.y * b.y + a.z * b.z + a.w * b.w;
}

// ---------------------------------------------------------------------------
// Kernel 2: pure streaming pass, one row per wave, UNCONDITIONAL (no count
// dependency, no branch — r0's proven BW-bound rowstats shape, 8192 blocks).
// Computes both branch terms per row, writes the 256 KB t2 table.
//   t_b(r) = log( sum_{j kept_b} exp(sim[r,j]/T) ) - <hg_r, ebar_b>/(T*||hg_r||)
// ---------------------------------------------------------------------------
__global__ __launch_bounds__(256) void rowterms_kernel(const float* __restrict__ hg,
                                                       const float* __restrict__ sim,
                                                       float* __restrict__ ws) {
    const int wave = threadIdx.x >> 6;
    const int lane = threadIdx.x & 63;
    const int r    = blockIdx.x * 4 + wave;

    const float4* eb4 = (const float4*)ws;   // 128 f4 ebar_sz, 128 f4 ebar_nsz
    const float4 es0 = eb4[lane * 2],       es1 = eb4[lane * 2 + 1];
    const float4 en0 = eb4[128 + lane * 2], en1 = eb4[128 + lane * 2 + 1];
    const unsigned msz  = ((const unsigned*)ws)[1024];
    const unsigned mnsz = ((const unsigned*)ws)[1025];

    const float4* rp = (const float4*)hg + (size_t)r * (LDIM / 4) + lane * 2;
    const float4 a0 = rp[0];
    const float4 a1 = rp[1];

    const bool  c20 = lane < NCON;
    const float sv  = c20 ? sim[(size_t)r * NCON + lane] : 0.f;

    float ss = dot4(a0, a0) + dot4(a1, a1);
    float ds = dot4(a0, es0) + dot4(a1, es1);
    float dn = dot4(a0, en0) + dot4(a1, en1);

    const float invT = 1.0f / TEMP_F;
    const float ex = expf(sv * invT);
    float e_s = (c20 && (msz  & (1u << lane))) ? ex : 0.f;
    float e_n = (c20 && (mnsz & (1u << lane))) ? ex : 0.f;

#pragma unroll
    for (int off = 32; off; off >>= 1) {
        ss  += __shfl_xor(ss, off);
        ds  += __shfl_xor(ds, off);
        dn  += __shfl_xor(dn, off);
        e_s += __shfl_xor(e_s, off);
        e_n += __shfl_xor(e_n, off);
    }

    if (lane == 0) {
        const float rn = invT / fmaxf(sqrtf(ss), 1e-12f);
        ((float2*)(ws + 2048))[r] = make_float2(logf(e_s) - ds * rn,
                                                logf(e_n) - dn * rn);
    }
}

// ---------------------------------------------------------------------------
// Kernel 3: selection gather + reduce. 128 blocks x 256 = 32768 threads,
// one selection each (sz for t<16384, nsz above — wave-uniform split).
// Gather is a single 4B read from the L2-resident 256 KB table.
// 128 same-address atomics total (proven free in r0).
// ---------------------------------------------------------------------------
__global__ __launch_bounds__(256) void gather_kernel(const int* __restrict__ sz_idx,
                                                     const int* __restrict__ nsz_idx,
                                                     const float* __restrict__ ws,
                                                     float* __restrict__ out) {
    const float2* t2 = (const float2*)(ws + 2048);
    const int t = blockIdx.x * 256 + threadIdx.x;

    float v;
    if (t < NSEL) v = t2[sz_idx[t]].x;
    else          v = t2[nsz_idx[t - NSEL]].y;

#pragma unroll
    for (int off = 32; off; off >>= 1) v += __shfl_xor(v, off);

    __shared__ float red[4];
    const int lane = threadIdx.x & 63;
    const int w    = threadIdx.x >> 6;
    if (lane == 0) red[w] = v;
    __syncthreads();
    if (threadIdx.x == 0)
        atomicAdd(out, (red[0] + red[1] + red[2] + red[3]) * (1.0f / NSEL));
}

extern "C" void kernel_launch(void* const* d_in, const int* in_sizes, int n_in,
                              void* d_out, int out_size, void* d_ws, size_t ws_size,
                              hipStream_t stream) {
    const float* hg      = (const float*)d_in[0];
    const float* hg_corr = (const float*)d_in[1];
    const float* all_emb = (const float*)d_in[2];
    const int*   sz_idx  = (const int*)d_in[3];
    const int*   nsz_idx = (const int*)d_in[4];
    const int*   Psz     = (const int*)d_in[5];
    const int*   Pnsz    = (const int*)d_in[6];
    float* out = (float*)d_out;
    float* ws  = (float*)d_ws;

    prep_kernel<<<1, 512, 0, stream>>>(all_emb, Psz, Pnsz, ws, out);
    rowterms_kernel<<<8192, 256, 0, stream>>>(hg, hg_corr, ws);
    gather_kernel<<<128, 256, 0, stream>>>(sz_idx, nsz_idx, ws, out);
}